// Round 11
// baseline (86.609 us; speedup 1.0000x reference)
//
#include <hip/hip_runtime.h>

#define B_    8
#define C_    64
#define O_    64
#define H_    128
#define W_    128
#define HW_   (H_ * W_)
#define NOFF_ 18
#define KK_   9
#define TR_   19      // staged rows  (8 + 5 + 5 + 1)
#define TC_   26      // staged cols  (16 + 5 + 4 + 1)

typedef __attribute__((ext_vector_type(8))) _Float16 f16x8;
typedef __attribute__((ext_vector_type(2))) _Float16 f16x2;
typedef __attribute__((ext_vector_type(4))) unsigned int u32x4;
typedef __attribute__((ext_vector_type(4))) float f32x4;
typedef unsigned int uint32;
typedef unsigned short ushort;

__device__ __forceinline__ f16x2 u2h(uint32 u) {
    union { uint32 u; f16x2 h; } c; c.u = u; return c.h;
}
__device__ __forceinline__ f16x8 u2h8(u32x4 q) {
    union { u32x4 u; f16x8 h; } c; c.u = q; return c.h;
}

// asm-pinned 16B global loads. "=&v" early-clobber (R6 lesson).
#define GLOAD16(dst, a64) \
    asm volatile("global_load_dwordx4 %0, %1, off" : "=&v"(dst) : "v"(a64) : "memory")
#define WAITV(N) do { \
    asm volatile("s_waitcnt vmcnt(" #N ")" ::: "memory"); \
    __builtin_amdgcn_sched_barrier(0); } while (0)
#define DRAIN_ALL() do { \
    asm volatile("s_waitcnt vmcnt(0) lgkmcnt(0)" ::: "memory"); \
    __builtin_amdgcn_sched_barrier(0); } while (0)

// ---------------------------------------------------------------------------
// x [b][c][hw] f32  ->  xT [b][hw][c] f16   (LDS tile transpose)
// ---------------------------------------------------------------------------
__global__ __launch_bounds__(256) void transpose_x(
    const float* __restrict__ x, _Float16* __restrict__ xT)
{
    __shared__ float tile[64][65];
    int blk = blockIdx.x;
    int b   = blk >> 8;
    int hw0 = (blk & 255) * 64;
    int t   = threadIdx.x;
    int q   = t >> 6;
    int ln  = t & 63;
#pragma unroll
    for (int p = 0; p < 16; ++p) {
        int c = p * 4 + q;
        tile[c][ln] = x[((size_t)(b * C_ + c) << 14) + hw0 + ln];
    }
    __syncthreads();
#pragma unroll
    for (int p = 0; p < 16; ++p) {
        int hw = p * 4 + q;
        xT[(((size_t)b << 14) + hw0 + hw) * 64 + ln] = (_Float16)tile[ln][hw];
    }
}

// ---------------------------------------------------------------------------
// Weight fragments (f16).
// ---------------------------------------------------------------------------
__global__ __launch_bounds__(256) void prep3(
    const float* __restrict__ w_conv, const float* __restrict__ w_off,
    _Float16* __restrict__ wfrag, _Float16* __restrict__ wofff)
{
    int idx = blockIdx.x * 256 + threadIdx.x;
    if (idx < 36864) {
        int i    = idx & 7;
        int lane = (idx >> 3) & 63;
        int nb   = (idx >> 9) & 3;
        int kc   = (idx >> 11) & 1;
        int kk   = idx >> 12;
        int c = kc * 32 + ((lane >> 4) << 3) + i;
        int o = nb * 16 + (lane & 15);
        wfrag[idx] = (_Float16)w_conv[(o * C_ + c) * 9 + kk];
    }
    if (idx < 18432) {
        int i    = idx & 7;
        int lane = (idx >> 3) & 63;
        int nb   = (idx >> 9) & 1;
        int kc   = (idx >> 10) & 1;
        int kk   = idx >> 11;
        int m = nb * 16 + (lane & 15);
        int c = kc * 32 + ((lane >> 4) << 3) + i;
        wofff[idx] = (_Float16)((m < NOFF_) ? w_off[(m * C_ + c) * 9 + kk] : 0.0f);
    }
}

// ---------------------------------------------------------------------------
// Offset conv (R7-proven, unchanged).
// ---------------------------------------------------------------------------
__global__ __launch_bounds__(512, 2) void offconv_mfma5(
    const _Float16* __restrict__ xT, const _Float16* __restrict__ wofff,
    const float* __restrict__ b_off, _Float16* __restrict__ offsh)
{
    __shared__ _Float16 wlds[18432];
    int t = threadIdx.x;
    {
        const u32x4* src = (const u32x4*)wofff;
        u32x4* dst = (u32x4*)wlds;
#pragma unroll
        for (int r = 0; r < 5; ++r) {
            int i = r * 512 + t;
            if (i < 2304) dst[i] = src[i];
        }
    }
    DRAIN_ALL();
    __syncthreads();

    int blk  = blockIdx.x;
    int b    = blk & 7;
    int hw0  = (blk >> 3) * 128;
    int lane = t & 63;
    int wv   = t >> 6;
    int pxb  = hw0 + wv * 16;
    int pr   = lane & 15;
    int g    = lane >> 4;
    int px   = pxb + pr;
    int h = px >> 7, w = px & (W_ - 1);
    const _Float16* xb = xT + (((size_t)b << 14) << 6);

    f32x4 acc[2];
#pragma unroll
    for (int nb = 0; nb < 2; ++nb) acc[nb] = (f32x4){0.f, 0.f, 0.f, 0.f};

    u32x4 q[3][2];
    bool  vld[3];

    auto issueO = [&](int kk, int st) {
        int ky = kk / 3, kx = kk % 3;
        int yy = h - 1 + ky, xx = w - 1 + kx;
        vld[st] = ((unsigned)yy < (unsigned)H_) && ((unsigned)xx < (unsigned)W_);
        int src = (min(max(yy, 0), H_ - 1) << 7) + min(max(xx, 0), W_ - 1);
        unsigned long long a = (unsigned long long)(xb + ((size_t)src << 6) + g * 8);
        GLOAD16(q[st][0], a);
        unsigned long long a2 = a + 64;
        GLOAD16(q[st][1], a2);
    };

    issueO(0, 0); issueO(1, 1); issueO(2, 2);
#pragma unroll
    for (int kk = 0; kk < KK_; ++kk) {
        const int s = kk % 3;
        if (kk < 7)      { WAITV(4); }
        else if (kk < 8) { WAITV(2); }
        else             { WAITV(0); }
#pragma unroll
        for (int kc = 0; kc < 2; ++kc) {
            f16x8 a = u2h8(q[s][kc]);
            f16x8 z = {};
            a = vld[s] ? a : z;
#pragma unroll
            for (int nb = 0; nb < 2; ++nb) {
                f16x8 bfr = *(const f16x8*)(wlds +
                    ((((kk * 2 + kc) << 1) + nb) << 9) + (lane << 3));
                acc[nb] = __builtin_amdgcn_mfma_f32_16x16x32_f16(a, bfr, acc[nb], 0, 0, 0);
            }
        }
        if (kk < 6) issueO(kk + 3, s);
    }

#pragma unroll
    for (int nb = 0; nb < 2; ++nb) {
        int m = nb * 16 + pr;
        if (m < NOFF_) {
            float bias = b_off[m];
#pragma unroll
            for (int r = 0; r < 4; ++r) {
                int prow = pxb + g * 4 + r;
                offsh[(size_t)((b << 14) + prow) * NOFF_ + m] = (_Float16)(acc[nb][r] + bias);
            }
        }
    }
}

// ---------------------------------------------------------------------------
// Deformable conv R11: wave = 32 px x 32 o. Per-wave weights (36 frags,
// 144 VGPR) loaded ONCE -> main-loop common path has ZERO VMEM and ZERO asm
// fences (plain LDS reads + VALU + MFMA; compiler pipelines across kk).
// Block = 8x16 px, 8 waves, 19x26 clamped x-neighborhood in 63.2 KB LDS
// (2 blocks/CU = 16 waves). Rare out-of-window: per-mtile global fallback.
// ---------------------------------------------------------------------------
__global__ __launch_bounds__(512, 2) void deform_mfma11(
    const _Float16* __restrict__ xT, const _Float16* __restrict__ offsh,
    const _Float16* __restrict__ wfrag, float* __restrict__ out)
{
    __shared__ _Float16 tile_s[TR_ * TC_ * 64];   // 63,232 B
    char* tilec = (char*)tile_s;

    int t    = threadIdx.x;
    int lane = t & 63;
    int wv   = t >> 6;
    int blk  = blockIdx.x;
    int b    = blk & 7;                   // XCD-aligned batch
    int tid  = blk >> 3;                  // 0..127
    int ty   = tid >> 3, tx = tid & 7;
    int pxg  = wv & 3;                    // px-group: local rows 2pxg, 2pxg+1
    int oh   = wv >> 2;                   // o-half: o in [32oh, 32oh+32)
    int ry0  = ty * 8 - 5;
    int cx0  = tx * 16 - 5;
    int colp = lane & 15;                 // pixel column this lane samples (A-row)
    int gg   = lane >> 4;                 // k-group (A chunk)
    const _Float16* xb = xT + (((size_t)b << 14) << 6);

    // ---- stage clamped 19x26 neighborhood (coalesced, swizzled) ----
#pragma unroll
    for (int it = 0; it < 8; ++it) {
        int idx = it * 512 + t;
        if (idx < TR_ * TC_ * 8) {
            int rl = idx >> 3, cg = idx & 7;
            int r  = rl / TC_, c = rl - r * TC_;
            int yy = min(max(ry0 + r, 0), H_ - 1);
            int xx = min(max(cx0 + c, 0), W_ - 1);
            u32x4 v = *(const u32x4*)(xb + (((size_t)((yy << 7) + xx)) << 6) + (cg << 3));
            int bo = ((rl << 7) + (cg << 4)) ^ ((rl & 7) << 4);
            *(u32x4*)(tilec + bo) = v;
        }
    }

    // ---- per-wave weights -> registers (36 frags = 144 VGPR), loaded once ----
    u32x4 wreg[9][2][2];
#pragma unroll
    for (int kk = 0; kk < 9; ++kk)
#pragma unroll
        for (int kc = 0; kc < 2; ++kc)
#pragma unroll
            for (int j = 0; j < 2; ++j)
                wreg[kk][kc][j] = *(const u32x4*)(wfrag +
                    ((((kk * 2 + kc) << 2) + oh * 2 + j) << 9) + (lane << 3));

    // ---- offsets for this lane's two pixels ----
    int rowA = ty * 8 + 2 * pxg;
    int colI = tx * 16 + colp;
    const uint32* obuA = (const uint32*)(offsh +
        (size_t)((b << 14) + (rowA << 7) + colI) * NOFF_);
    const uint32* obuB = (const uint32*)(offsh +
        (size_t)((b << 14) + ((rowA + 1) << 7) + colI) * NOFF_);
    uint32 dpkA[9], dpkB[9];
#pragma unroll
    for (int kk = 0; kk < 9; ++kk) { dpkA[kk] = obuA[kk]; dpkB[kk] = obuB[kk]; }

    DRAIN_ALL();
    __syncthreads();

    f32x4 acc00 = {0.f,0.f,0.f,0.f}, acc01 = {0.f,0.f,0.f,0.f};
    f32x4 acc10 = {0.f,0.f,0.f,0.f}, acc11 = {0.f,0.f,0.f,0.f};

    // per-pixel bilinear prep
    auto prepPx = [&](uint32 du, int row_img, int col_img, int ky, int kx,
                      f16x2* Wc, int* rl, int* yc, int* xc) -> int {
        union { uint32 u; f16x2 hh; } cv; cv.u = du;
        float dyv = (float)cv.hh[0], dxv = (float)cv.hh[1];
        float py  = (float)(row_img - 1 + ky) + dyv;
        float pxf = (float)(col_img - 1 + kx) + dxv;
        float y0f = floorf(py), x0f = floorf(pxf);
        float ly = py - y0f, lx = pxf - x0f;
        int y0 = (int)y0f, x0 = (int)x0f;
        float w00 = (1.f - ly) * (1.f - lx);
        float w01 = (1.f - ly) * lx;
        float w10 = ly * (1.f - lx);
        float w11 = ly * lx;
        bool vy0 = (unsigned)y0       < (unsigned)H_;
        bool vy1 = (unsigned)(y0 + 1) < (unsigned)H_;
        bool vx0 = (unsigned)x0       < (unsigned)W_;
        bool vx1 = (unsigned)(x0 + 1) < (unsigned)W_;
        if (!(vy0 && vx0)) w00 = 0.f;
        if (!(vy0 && vx1)) w01 = 0.f;
        if (!(vy1 && vx0)) w10 = 0.f;
        if (!(vy1 && vx1)) w11 = 0.f;
        int yc0 = min(max(y0, 0), H_ - 1);
        int yc1 = min(max(y0 + 1, 0), H_ - 1);
        int xc0 = min(max(x0, 0), W_ - 1);
        int xc1 = min(max(x0 + 1, 0), W_ - 1);
        Wc[0] = (f16x2){(_Float16)w00, (_Float16)w00};
        Wc[1] = (f16x2){(_Float16)w01, (_Float16)w01};
        Wc[2] = (f16x2){(_Float16)w10, (_Float16)w10};
        Wc[3] = (f16x2){(_Float16)w11, (_Float16)w11};
        yc[0] = yc0; yc[1] = yc1; xc[0] = xc0; xc[1] = xc1;
        int r0 = yc0 - ry0, r1 = yc1 - ry0;
        int c0 = xc0 - cx0, c1 = xc1 - cx0;
        rl[0] = r0 * TC_ + c0; rl[1] = r0 * TC_ + c1;
        rl[2] = r1 * TC_ + c0; rl[3] = r1 * TC_ + c1;
        return ((unsigned)r0 >= TR_ - 1) | ((unsigned)r1 >= TR_) |
               ((unsigned)c0 >= TC_ - 1) | ((unsigned)c1 >= TC_);
    };

#pragma unroll
    for (int kk = 0; kk < KK_; ++kk) {
        const int ky = kk / 3, kx = kk % 3;

#pragma unroll
        for (int mt = 0; mt < 2; ++mt) {
            f16x2 Wc[4]; int rl[4], yc[2], xc[2];
            int bad = prepPx(mt ? dpkB[kk] : dpkA[kk], rowA + mt, colI, ky, kx,
                             Wc, rl, yc, xc);
            u32x4 q[8];                    // [kc*4 + corner]
            if (!__any(bad)) {
                // LDS gather (swizzled) — plain loads, compiler-scheduled
#pragma unroll
                for (int kc = 0; kc < 2; ++kc) {
                    int ch = ((kc << 2) + gg) << 4;
#pragma unroll
                    for (int cr = 0; cr < 4; ++cr) {
                        int bo = (((rl[cr]) << 7) + ch) ^ ((rl[cr] & 7) << 4);
                        q[kc * 4 + cr] = *(const u32x4*)(tilec + bo);
                    }
                }
            } else {
                // rare fallback: exact global gathers + drain own loads
#pragma unroll
                for (int kc = 0; kc < 2; ++kc) {
                    int ce = ((kc << 2) + gg) << 3;
#pragma unroll
                    for (int cr = 0; cr < 4; ++cr) {
                        int yy = yc[cr >> 1], xx = xc[cr & 1];
                        unsigned long long a = (unsigned long long)(xb +
                            (((size_t)((yy << 7) + xx)) << 6) + ce);
                        GLOAD16(q[kc * 4 + cr], a);
                    }
                }
                WAITV(0);
            }
            // bilerp + MFMA
#pragma unroll
            for (int kc = 0; kc < 2; ++kc) {
                f16x8 a;
                f16x2* ap = (f16x2*)&a;
#pragma unroll
                for (int p4 = 0; p4 < 4; ++p4) {
                    ap[p4] = u2h(q[kc * 4 + 0][p4]) * Wc[0]
                           + u2h(q[kc * 4 + 1][p4]) * Wc[1]
                           + u2h(q[kc * 4 + 2][p4]) * Wc[2]
                           + u2h(q[kc * 4 + 3][p4]) * Wc[3];
                }
                if (mt == 0) {
                    acc00 = __builtin_amdgcn_mfma_f32_16x16x32_f16(a, u2h8(wreg[kk][kc][0]), acc00, 0, 0, 0);
                    acc01 = __builtin_amdgcn_mfma_f32_16x16x32_f16(a, u2h8(wreg[kk][kc][1]), acc01, 0, 0, 0);
                } else {
                    acc10 = __builtin_amdgcn_mfma_f32_16x16x32_f16(a, u2h8(wreg[kk][kc][0]), acc10, 0, 0, 0);
                    acc11 = __builtin_amdgcn_mfma_f32_16x16x32_f16(a, u2h8(wreg[kk][kc][1]), acc11, 0, 0, 0);
                }
            }
        }
    }

    // C/D: col=lane&15 -> o-within-16; row=(lane>>4)*4+r -> px col; 16B stores
    int ocol0 = tx * 16 + (gg << 2);
#pragma unroll
    for (int mt = 0; mt < 2; ++mt) {
        int orow = rowA + mt;
#pragma unroll
        for (int j = 0; j < 2; ++j) {
            int o = oh * 32 + j * 16 + colp;
            f32x4 v = mt ? (j ? acc11 : acc10) : (j ? acc01 : acc00);
            float* outp = out + (((size_t)(b * O_ + o)) << 14) + (orow << 7) + ocol0;
            *(f32x4*)outp = v;
        }
    }
}

// ===========================================================================
extern "C" void kernel_launch(void* const* d_in, const int* in_sizes, int n_in,
                              void* d_out, int out_size, void* d_ws, size_t ws_size,
                              hipStream_t stream)
{
    const float* x      = (const float*)d_in[0];
    const float* w_off  = (const float*)d_in[1];
    const float* b_off  = (const float*)d_in[2];
    const float* w_conv = (const float*)d_in[3];
    float* out = (float*)d_out;
    char* ws = (char*)d_ws;

    // workspace layout (bytes) — total 21,643,264
    const size_t XT_OFF    = 0;           // 16,777,216  f16 NHWC x
    const size_t OFFS_OFF  = 16777216;    //  4,718,592  f16 NHWC offsets
    const size_t WFRAG_OFF = 21495808;    //     73,728  deform weight frags
    const size_t WOFF_OFF  = 21569536;    //     36,864  offset weight frags

    _Float16* xT    = (_Float16*)(ws + XT_OFF);
    _Float16* offsh = (_Float16*)(ws + OFFS_OFF);
    _Float16* wfrag = (_Float16*)(ws + WFRAG_OFF);
    _Float16* wofff = (_Float16*)(ws + WOFF_OFF);

    transpose_x  <<<2048, 256, 0, stream>>>(x, xT);
    prep3        <<<144, 256, 0, stream>>>(w_conv, w_off, wfrag, wofff);
    offconv_mfma5<<<1024, 512, 0, stream>>>(xT, wofff, b_off, offsh);
    deform_mfma11<<<1024, 512, 0, stream>>>(xT, offsh, wfrag, out);
}

// Round 12
// 65.611 us; speedup vs baseline: 1.3200x; 1.3200x over previous
//
#include <hip/hip_runtime.h>

#define B_    8
#define C_    64
#define O_    64
#define H_    128
#define W_    128
#define HW_   (H_ * W_)
#define NOFF_ 18
#define KK_   9
#define TW_   19       // staged tile span (8 + 2*5 + 1)
#define PADW_ 5
#define RSTR_ 144      // LDS row stride in bytes (128 + 16, conflict-free)

typedef __attribute__((ext_vector_type(8))) _Float16 f16x8;
typedef __attribute__((ext_vector_type(2))) _Float16 f16x2;
typedef __attribute__((ext_vector_type(4))) unsigned int u32x4;
typedef __attribute__((ext_vector_type(4))) float f32x4;
typedef unsigned int uint32;
typedef unsigned short ushort;

__device__ __forceinline__ f16x2 u2h(uint32 u) {
    union { uint32 u; f16x2 h; } c; c.u = u; return c.h;
}
__device__ __forceinline__ f16x8 u2h8(u32x4 q) {
    union { u32x4 u; f16x8 h; } c; c.u = q; return c.h;
}

// asm-pinned 16B global loads. "=&v" early-clobber (R6 lesson).
#define GLOAD16(dst, a64) \
    asm volatile("global_load_dwordx4 %0, %1, off" : "=&v"(dst) : "v"(a64) : "memory")
// counted wait TIED to the 8 weight regs: consumers ordered by data-dep,
// everything else (LDS reads, VALU prep, bilerp) remains schedulable.
#define WAITV_TIE(N, w) \
    asm volatile("s_waitcnt vmcnt(" #N ")" \
        : "+v"(w[0]), "+v"(w[1]), "+v"(w[2]), "+v"(w[3]), \
          "+v"(w[4]), "+v"(w[5]), "+v"(w[6]), "+v"(w[7]))
#define WAITV(N) do { \
    asm volatile("s_waitcnt vmcnt(" #N ")" ::: "memory"); \
    __builtin_amdgcn_sched_barrier(0); } while (0)
#define DRAIN_ALL() do { \
    asm volatile("s_waitcnt vmcnt(0) lgkmcnt(0)" ::: "memory"); \
    __builtin_amdgcn_sched_barrier(0); } while (0)

// ---------------------------------------------------------------------------
// x [b][c][hw] f32  ->  xT [b][hw][c] f16   (LDS tile transpose)
// ---------------------------------------------------------------------------
__global__ __launch_bounds__(256) void transpose_x(
    const float* __restrict__ x, _Float16* __restrict__ xT)
{
    __shared__ float tile[64][65];
    int blk = blockIdx.x;
    int b   = blk >> 8;
    int hw0 = (blk & 255) * 64;
    int t   = threadIdx.x;
    int q   = t >> 6;
    int ln  = t & 63;
#pragma unroll
    for (int p = 0; p < 16; ++p) {
        int c = p * 4 + q;
        tile[c][ln] = x[((size_t)(b * C_ + c) << 14) + hw0 + ln];
    }
    __syncthreads();
#pragma unroll
    for (int p = 0; p < 16; ++p) {
        int hw = p * 4 + q;
        xT[(((size_t)b << 14) + hw0 + hw) * 64 + ln] = (_Float16)tile[ln][hw];
    }
}

// ---------------------------------------------------------------------------
// Weight fragments (f16).
// ---------------------------------------------------------------------------
__global__ __launch_bounds__(256) void prep3(
    const float* __restrict__ w_conv, const float* __restrict__ w_off,
    _Float16* __restrict__ wfrag, _Float16* __restrict__ wofff)
{
    int idx = blockIdx.x * 256 + threadIdx.x;
    if (idx < 36864) {
        int i    = idx & 7;
        int lane = (idx >> 3) & 63;
        int nb   = (idx >> 9) & 3;
        int kc   = (idx >> 11) & 1;
        int kk   = idx >> 12;
        int c = kc * 32 + ((lane >> 4) << 3) + i;
        int o = nb * 16 + (lane & 15);
        wfrag[idx] = (_Float16)w_conv[(o * C_ + c) * 9 + kk];
    }
    if (idx < 18432) {
        int i    = idx & 7;
        int lane = (idx >> 3) & 63;
        int nb   = (idx >> 9) & 1;
        int kc   = (idx >> 10) & 1;
        int kk   = idx >> 11;
        int m = nb * 16 + (lane & 15);
        int c = kc * 32 + ((lane >> 4) << 3) + i;
        wofff[idx] = (_Float16)((m < NOFF_) ? w_off[(m * C_ + c) * 9 + kk] : 0.0f);
    }
}

// ---------------------------------------------------------------------------
// Offset conv (R7-proven, unchanged).
// ---------------------------------------------------------------------------
__global__ __launch_bounds__(512, 2) void offconv_mfma5(
    const _Float16* __restrict__ xT, const _Float16* __restrict__ wofff,
    const float* __restrict__ b_off, _Float16* __restrict__ offsh)
{
    __shared__ _Float16 wlds[18432];
    int t = threadIdx.x;
    {
        const u32x4* src = (const u32x4*)wofff;
        u32x4* dst = (u32x4*)wlds;
#pragma unroll
        for (int r = 0; r < 5; ++r) {
            int i = r * 512 + t;
            if (i < 2304) dst[i] = src[i];
        }
    }
    DRAIN_ALL();
    __syncthreads();

    int blk  = blockIdx.x;
    int b    = blk & 7;
    int hw0  = (blk >> 3) * 128;
    int lane = t & 63;
    int wv   = t >> 6;
    int pxb  = hw0 + wv * 16;
    int pr   = lane & 15;
    int g    = lane >> 4;
    int px   = pxb + pr;
    int h = px >> 7, w = px & (W_ - 1);
    const _Float16* xb = xT + (((size_t)b << 14) << 6);

    f32x4 acc[2];
#pragma unroll
    for (int nb = 0; nb < 2; ++nb) acc[nb] = (f32x4){0.f, 0.f, 0.f, 0.f};

    u32x4 q[3][2];
    bool  vld[3];

    auto issueO = [&](int kk, int st) {
        int ky = kk / 3, kx = kk % 3;
        int yy = h - 1 + ky, xx = w - 1 + kx;
        vld[st] = ((unsigned)yy < (unsigned)H_) && ((unsigned)xx < (unsigned)W_);
        int src = (min(max(yy, 0), H_ - 1) << 7) + min(max(xx, 0), W_ - 1);
        unsigned long long a = (unsigned long long)(xb + ((size_t)src << 6) + g * 8);
        GLOAD16(q[st][0], a);
        unsigned long long a2 = a + 64;
        GLOAD16(q[st][1], a2);
    };

    issueO(0, 0); issueO(1, 1); issueO(2, 2);
#pragma unroll
    for (int kk = 0; kk < KK_; ++kk) {
        const int s = kk % 3;
        if (kk < 7)      { WAITV(4); }
        else if (kk < 8) { WAITV(2); }
        else             { WAITV(0); }
#pragma unroll
        for (int kc = 0; kc < 2; ++kc) {
            f16x8 a = u2h8(q[s][kc]);
            f16x8 z = {};
            a = vld[s] ? a : z;
#pragma unroll
            for (int nb = 0; nb < 2; ++nb) {
                f16x8 bfr = *(const f16x8*)(wlds +
                    ((((kk * 2 + kc) << 1) + nb) << 9) + (lane << 3));
                acc[nb] = __builtin_amdgcn_mfma_f32_16x16x32_f16(a, bfr, acc[nb], 0, 0, 0);
            }
        }
        if (kk < 6) issueO(kk + 3, s);
    }

#pragma unroll
    for (int nb = 0; nb < 2; ++nb) {
        int m = nb * 16 + pr;
        if (m < NOFF_) {
            float bias = b_off[m];
#pragma unroll
            for (int r = 0; r < 4; ++r) {
                int prow = pxb + g * 4 + r;
                offsh[(size_t)((b << 14) + prow) * NOFF_ + m] = (_Float16)(acc[nb][r] + bias);
            }
        }
    }
}

// ---------------------------------------------------------------------------
// Deformable conv R12: R10 dataflow (8x8 px/block, 19x19 LDS x-tile), plus:
//  - row stride 144B (non-pow2) -> <=2-way bank aliasing (free)
//  - weight double-buffer, tie-waited vmcnt(8): no sched_barrier in the loop,
//    compiler free to software-pipeline LDS reads / prep / bilerp across kk.
// ---------------------------------------------------------------------------
__global__ __launch_bounds__(256, 3) void deform_mfma10(
    const _Float16* __restrict__ xT, const _Float16* __restrict__ offsh,
    const _Float16* __restrict__ wfrag, float* __restrict__ out)
{
    __shared__ char tilec[TW_ * TW_ * RSTR_];   // 51,984 B

    int t    = threadIdx.x;
    int blk  = blockIdx.x;
    int b    = blk & 7;                       // XCD-aligned batch
    int tid  = blk >> 3;                      // 0..255 tile id
    int ty   = tid >> 4, tx = tid & 15;
    int lane = t & 63;
    int wv   = t >> 6;
    int pr   = lane & 15;                     // fragment px row
    int gg   = lane >> 4;                     // fragment k-group
    int ry0  = ty * 8 - PADW_;
    int cx0  = tx * 8 - PADW_;
    const _Float16* xb = xT + (((size_t)b << 14) << 6);

    // ---- stage clamped 19x19 neighborhood (coalesced, stride-144 rows) ----
#pragma unroll
    for (int it = 0; it < 12; ++it) {
        int idx = it * 256 + t;
        if (idx < TW_ * TW_ * 8) {
            int i   = idx / (TW_ * 8);
            int rem = idx - i * (TW_ * 8);
            int j   = rem >> 3, cg = rem & 7;
            int yy = min(max(ry0 + i, 0), H_ - 1);
            int xx = min(max(cx0 + j, 0), W_ - 1);
            u32x4 v = *(const u32x4*)(xb + (((size_t)((yy << 7) + xx)) << 6) + (cg << 3));
            int rl = i * TW_ + j;
            *(u32x4*)(tilec + rl * RSTR_ + (cg << 4)) = v;
        }
    }

    // per-lane pixel (fragment role) + its 9 offset pairs
    int h_img = ty * 8 + wv * 2 + (pr >> 3);
    int w_img = tx * 8 + (pr & 7);
    const uint32* obu = (const uint32*)(offsh +
        (size_t)((b << 14) + (h_img << 7) + w_img) * NOFF_);
    uint32 dpk[9];
#pragma unroll
    for (int kk = 0; kk < 9; ++kk) dpk[kk] = obu[kk];
    DRAIN_ALL();
    __syncthreads();

    f32x4 acc[4];
#pragma unroll
    for (int nb = 0; nb < 4; ++nb) acc[nb] = (f32x4){0.f, 0.f, 0.f, 0.f};

    u32x4 wqA[8], wqB[8];   // weight double-buffer (static names, rule #20)
    u32x4 q[8];             // corner data [kc*4 + corner]

    // issue weights for kk: 8 coalesced 1KB loads
    auto issueW = [&](int kk, u32x4* wq) {
#pragma unroll
        for (int f = 0; f < 8; ++f) {         // f = kc*4 + nb
            unsigned long long wa = (unsigned long long)(wfrag +
                ((((kk * 2 + (f >> 2)) << 2) + (f & 3)) << 9) + (lane << 3));
            GLOAD16(wq[f], wa);
        }
    };

    issueW(0, wqA);
#pragma unroll
    for (int kk = 0; kk < KK_; ++kk) {
        u32x4* wcur = (kk & 1) ? wqB : wqA;
        u32x4* wnxt = (kk & 1) ? wqA : wqB;
        if (kk < 8) issueW(kk + 1, wnxt);

        // bilinear prep for this lane's own pixel (pure VALU, schedulable)
        int ky = kk / 3, kx = kk % 3;
        union { uint32 u; f16x2 hh; } cv; cv.u = dpk[kk];
        float dyv = (float)cv.hh[0], dxv = (float)cv.hh[1];
        float py  = (float)(h_img - 1 + ky) + dyv;
        float pxf = (float)(w_img - 1 + kx) + dxv;
        float y0f = floorf(py), x0f = floorf(pxf);
        float ly = py - y0f, lx = pxf - x0f;
        int y0 = (int)y0f, x0 = (int)x0f;
        float w00 = (1.f - ly) * (1.f - lx);
        float w01 = (1.f - ly) * lx;
        float w10 = ly * (1.f - lx);
        float w11 = ly * lx;
        bool vy0 = (unsigned)y0       < (unsigned)H_;
        bool vy1 = (unsigned)(y0 + 1) < (unsigned)H_;
        bool vx0 = (unsigned)x0       < (unsigned)W_;
        bool vx1 = (unsigned)(x0 + 1) < (unsigned)W_;
        if (!(vy0 && vx0)) w00 = 0.f;
        if (!(vy0 && vx1)) w01 = 0.f;
        if (!(vy1 && vx0)) w10 = 0.f;
        if (!(vy1 && vx1)) w11 = 0.f;
        int yc0 = min(max(y0, 0), H_ - 1);
        int yc1 = min(max(y0 + 1, 0), H_ - 1);
        int xc0 = min(max(x0, 0), W_ - 1);
        int xc1 = min(max(x0 + 1, 0), W_ - 1);
        f16x2 Wc0 = (f16x2){(_Float16)w00, (_Float16)w00};
        f16x2 Wc1 = (f16x2){(_Float16)w01, (_Float16)w01};
        f16x2 Wc2 = (f16x2){(_Float16)w10, (_Float16)w10};
        f16x2 Wc3 = (f16x2){(_Float16)w11, (_Float16)w11};

        int r0 = yc0 - ry0, r1 = yc1 - ry0;
        int c0 = xc0 - cx0, c1 = xc1 - cx0;
        int bad = ((unsigned)r0 >= TW_) | ((unsigned)r1 >= TW_) |
                  ((unsigned)c0 >= TW_) | ((unsigned)c1 >= TW_);

        if (!__any(bad)) {
            // LDS gather: plain loads, stride-144 rows, compiler-scheduled
            int rl00 = r0 * TW_ + c0, rl01 = r0 * TW_ + c1;
            int rl10 = r1 * TW_ + c0, rl11 = r1 * TW_ + c1;
            int ch0 = gg << 4;
#pragma unroll
            for (int kc = 0; kc < 2; ++kc) {
                int ch = ch0 + (kc << 6);
                q[kc * 4 + 0] = *(const u32x4*)(tilec + rl00 * RSTR_ + ch);
                q[kc * 4 + 1] = *(const u32x4*)(tilec + rl01 * RSTR_ + ch);
                q[kc * 4 + 2] = *(const u32x4*)(tilec + rl10 * RSTR_ + ch);
                q[kc * 4 + 3] = *(const u32x4*)(tilec + rl11 * RSTR_ + ch);
            }
        } else {
            // rare fallback: exact global gathers, full drain (sched-pinned ok)
#pragma unroll
            for (int kc = 0; kc < 2; ++kc) {
                int ce = ((kc << 2) + gg) << 3;
                unsigned long long a00 = (unsigned long long)(xb + (((size_t)((yc0 << 7) + xc0)) << 6) + ce);
                unsigned long long a01 = (unsigned long long)(xb + (((size_t)((yc0 << 7) + xc1)) << 6) + ce);
                unsigned long long a10 = (unsigned long long)(xb + (((size_t)((yc1 << 7) + xc0)) << 6) + ce);
                unsigned long long a11 = (unsigned long long)(xb + (((size_t)((yc1 << 7) + xc1)) << 6) + ce);
                GLOAD16(q[kc * 4 + 0], a00);
                GLOAD16(q[kc * 4 + 1], a01);
                GLOAD16(q[kc * 4 + 2], a10);
                GLOAD16(q[kc * 4 + 3], a11);
            }
            WAITV(0);
        }

        // wait (tied) for THIS kk's weights: kk<8 -> next-kk's 8 still inflight
        if (kk < 8) { WAITV_TIE(8, wcur); } else { WAITV_TIE(0, wcur); }

        // bilerp + MFMA
#pragma unroll
        for (int kc = 0; kc < 2; ++kc) {
            f16x8 a;
            f16x2* ap = (f16x2*)&a;
#pragma unroll
            for (int p4 = 0; p4 < 4; ++p4) {
                ap[p4] = u2h(q[kc * 4 + 0][p4]) * Wc0
                       + u2h(q[kc * 4 + 1][p4]) * Wc1
                       + u2h(q[kc * 4 + 2][p4]) * Wc2
                       + u2h(q[kc * 4 + 3][p4]) * Wc3;
            }
#pragma unroll
            for (int nb = 0; nb < 4; ++nb) {
                acc[nb] = __builtin_amdgcn_mfma_f32_16x16x32_f16(
                    a, u2h8(wcur[kc * 4 + nb]), acc[nb], 0, 0, 0);
            }
        }
    }

    // C/D: col=lane&15 -> o; row=gg*4+r -> p_local -> (row pair, col quad)
#pragma unroll
    for (int nb = 0; nb < 4; ++nb) {
        int o = nb * 16 + pr;
        int orow = ty * 8 + wv * 2 + (gg >> 1);
        int ocol = tx * 8 + ((gg & 1) << 2);
        float* outp = out + (((size_t)(b * O_ + o)) << 14) + (orow << 7) + ocol;
        *(f32x4*)outp = acc[nb];
    }
}

// ===========================================================================
extern "C" void kernel_launch(void* const* d_in, const int* in_sizes, int n_in,
                              void* d_out, int out_size, void* d_ws, size_t ws_size,
                              hipStream_t stream)
{
    const float* x      = (const float*)d_in[0];
    const float* w_off  = (const float*)d_in[1];
    const float* b_off  = (const float*)d_in[2];
    const float* w_conv = (const float*)d_in[3];
    float* out = (float*)d_out;
    char* ws = (char*)d_ws;

    // workspace layout (bytes) — total 21,643,264
    const size_t XT_OFF    = 0;           // 16,777,216  f16 NHWC x
    const size_t OFFS_OFF  = 16777216;    //  4,718,592  f16 NHWC offsets
    const size_t WFRAG_OFF = 21495808;    //     73,728  deform weight frags
    const size_t WOFF_OFF  = 21569536;    //     36,864  offset weight frags

    _Float16* xT    = (_Float16*)(ws + XT_OFF);
    _Float16* offsh = (_Float16*)(ws + OFFS_OFF);
    _Float16* wfrag = (_Float16*)(ws + WFRAG_OFF);
    _Float16* wofff = (_Float16*)(ws + WOFF_OFF);

    transpose_x  <<<2048, 256, 0, stream>>>(x, xT);
    prep3        <<<144, 256, 0, stream>>>(w_conv, w_off, wfrag, wofff);
    offconv_mfma5<<<1024, 512, 0, stream>>>(xT, wofff, b_off, offsh);
    deform_mfma10<<<2048, 256, 0, stream>>>(xT, offsh, wfrag, out);
}